// Round 11
// baseline (1776.965 us; speedup 1.0000x reference)
//
#include <hip/hip_runtime.h>
#include <hip/hip_bf16.h>
#include <hip/hip_cooperative_groups.h>

namespace cg = cooperative_groups;

// EGNN forward, MI355X. fp32 tensors (runtime-detected, bf16 path kept).
// R21 = SINGLE COOPERATIVE MEGA-KERNEL.
//  - R20 fusion A/B decomposition: removing 5 dispatches cut the non-k_edge
//    side 280->160us (~24us/dispatch boundary+launch overhead). R17's
//    14-dispatch pipeline carries ~250us of pure boundary cost -- the
//    biggest remaining lever. One cooperative kernel + grid.sync removes
//    all 13 boundaries.
//  - R20's k_edge regression (+37us/dispatch from the serial per-node MLP
//    tail) is REVERTED: node MLP runs as a bulk phase (k_node-style, 4-node
//    ILP chunks, weights in LDS) separated from the edge phase by grid.sync.
//    Edge phase body = R17 verbatim (proven 67.5us @ 3 blocks/CU; here
//    2 blocks/CU). In-place h/x update is race-free across grid.sync.
//  - Deadlock-proof: grid = maxActiveBlocksPerCU * 256 via occupancy API
//    (expect 2/CU -> 512; graceful 256 fallback). All phases gridDim-generic.
//  - Numerics: operation-identical to R17 (edge/node/embed/out bodies copied).
// ws (floats): hws[N*64] | xws[N*3] | agg[N*64] | xacc[N*3]  (=134 exactly)
// d_out scratch until out phase:
//   hb[N*64 bf16] | offs[N+4] | slist[E] | pkE[4*17024 u16] | pkN[4*6272 u32] |
//   cursor[N] | perm[N]   (4.32MB <= 5.36MB)

#define NN 20000
#define EE 320000
#define LSE 17024
#define LSN 6272

typedef unsigned short u16;
typedef unsigned int   u32;
typedef __attribute__((ext_vector_type(8))) short s16x8;
typedef __attribute__((ext_vector_type(4))) float f32x4;

__device__ __forceinline__ float bf2f(u16 u) { return __uint_as_float(((u32)u) << 16); }
__device__ __forceinline__ float silu_f(float x) {
    return x * __builtin_amdgcn_rcpf(1.0f + __expf(-x));
}
__device__ __forceinline__ u16 f2bf_rne(float f) {
    u32 u = __float_as_uint(f);
    return (u16)((u + 0x7FFFu + ((u >> 16) & 1u)) >> 16);
}
__device__ __forceinline__ float gldf(const void* p, int i, int bf) {
    return bf ? bf2f(((const u16*)p)[i]) : ((const float*)p)[i];
}
__device__ __forceinline__ u16 gldb(const void* p, int i, int bf) {
    return bf ? ((const u16*)p)[i] : f2bf_rne(((const float*)p)[i]);
}

__global__ void k_sentinel(u16* __restrict__ out, int n, float v) {
    int t = blockIdx.x * 256 + threadIdx.x;
    if (t < n) out[t] = f2bf_rne(v);
}

// LDS layout (u16 units) -- identical to R20's footprint, 79104 B:
// [0..8192)      edge W1 (4 B-tile groups x 4t)
// [8192..16384)  edge W2|C1
// [16384..)      mrow: 8 waves x 16 x MPAD    (aliased: scan part/hist, node nin, out sH)
// OFF_PHI        8 waves x 32B phi slots
// OFF_CB         320 f32 edge consts
// OFF_NW         node W1(4096 u32)|W2(2048 u32)|biases(128 f32) = 12544 u16
#define OFF_B23  8192
#define OFF_M    16384
#define MPAD     76
#define OFF_PHI  (OFF_M + 8 * 16 * MPAD)
#define OFF_CB   (OFF_PHI + 8 * 32)
#define OFF_NW   (OFF_CB + 640)

__global__ __launch_bounds__(512, 2) void k_mega(
    const void* __restrict__ h_in, const void* __restrict__ x_in,
    const int* __restrict__ rowi, const int* __restrict__ coli,
    const void* __restrict__ ew1, const void* __restrict__ eb1,
    const void* __restrict__ ew2, const void* __restrict__ eb2,
    const void* __restrict__ cw1, const void* __restrict__ cb1,
    const void* __restrict__ cw2,
    const void* __restrict__ nw1, const void* __restrict__ nb1,
    const void* __restrict__ nw2, const void* __restrict__ nb2,
    const void* __restrict__ emb_w, const void* __restrict__ emb_b,
    const void* __restrict__ wo, const void* __restrict__ bo,
    float* __restrict__ hws, float* __restrict__ xws,
    float* __restrict__ agg, float* __restrict__ xacc,
    u16* __restrict__ hb, int* __restrict__ offs, int* __restrict__ slist,
    u16* __restrict__ pkE, u32* __restrict__ pkN,
    int* __restrict__ cursor, int* __restrict__ perm, void* __restrict__ outp)
{
    __shared__ __align__(16) u16 sW[OFF_NW + 12544];
    __shared__ int cnt_s;

    cg::grid_group grid = cg::this_grid();
    const int tid = threadIdx.x, bid = blockIdx.x;
    const int lane = tid & 63, wv = tid >> 6;
    const int l15 = lane & 15, quad = lane >> 4;
    const int gid = bid * 512 + tid;
    const int gthreads = gridDim.x * 512;
    const int nwaves = gthreads >> 6;
    const int waveid = gid >> 6;

    // ---- local dtype detection (per block, no global flag) ----
    if (tid == 0) cnt_s = 0;
    __syncthreads();
    if (tid < 128) {
        float v = fabsf(bf2f(((const u16*)h_in)[tid]));
        if (v >= 0.015625f && v <= 16.0f) atomicAdd(&cnt_s, 1);
    }
    __syncthreads();
    const int bf = (cnt_s >= 96) ? 1 : 0;

    // ---- P0: zero cursor ----
    for (int i = gid; i < NN; i += gthreads) cursor[i] = 0;
    __threadfence();
    grid.sync();

    // ---- P1: degree count + weight prepack ----
    for (int e = gid; e < EE; e += gthreads) atomicAdd(&cursor[rowi[e]], 1);
    for (int g = gid; g < 4 * 16384; g += gthreads) {
        int l = g >> 14, idx = g & 16383;
        u16 v;
        if (idx < 8192) {
            int j = idx & 7, ln = (idx >> 3) & 63, t = (idx >> 9) & 3, w = idx >> 11;
            int k = 32 * w + (ln >> 4) * 8 + j, n = 16 * t + (ln & 15);
            v = gldb(ew1, l * 129 * 64 + k * 64 + n, bf);
        } else if (idx < 12288) {
            int i2 = idx - 8192;
            int j = i2 & 7, ln = (i2 >> 3) & 63, t = (i2 >> 9) & 3, w = i2 >> 11;
            int k = 32 * w + (ln >> 4) * 8 + j, n = 16 * t + (ln & 15);
            v = gldb(ew2, l * 4096 + k * 64 + n, bf);
        } else {
            int i2 = idx - 12288;
            int j = i2 & 7, ln = (i2 >> 3) & 63, t = (i2 >> 9) & 3, w = i2 >> 11;
            int k = 32 * w + (ln >> 4) * 8 + j, n = 16 * t + (ln & 15);
            v = gldb(cw1, l * 4096 + k * 64 + n, bf);
        }
        pkE[l * LSE + idx] = v;
    }
    for (int g = gid; g < 4 * 320; g += gthreads) {
        int l = g / 320, r = g % 320, wch = r >> 6, i = r & 63;
        float v = (wch == 0) ? gldf(eb1, l * 64 + i, bf)
                : (wch == 1) ? gldf(eb2, l * 64 + i, bf)
                : (wch == 2) ? gldf(cb1, l * 64 + i, bf)
                : (wch == 3) ? gldf(cw2, l * 64 + i, bf)
                :              gldf(ew1, l * 129 * 64 + 128 * 64 + i, bf);
        ((float*)(pkE + l * LSE + 16384))[r] = v;
    }
    for (int g = gid; g < 4 * 6144; g += gthreads) {
        int l = g / 6144, idx = g % 6144;
        u32 pv;
        if (idx < 4096) {
            int kp = idx >> 6, j = idx & 63;
            u32 lo = gldb(nw1, l * 8192 + (2 * kp) * 64 + j, bf);
            u32 hi = gldb(nw1, l * 8192 + (2 * kp + 1) * 64 + j, bf);
            pv = lo | (hi << 16);
        } else {
            int i2 = idx - 4096, kp = i2 >> 6, j = i2 & 63;
            u32 lo = gldb(nw2, l * 4096 + (2 * kp) * 64 + j, bf);
            u32 hi = gldb(nw2, l * 4096 + (2 * kp + 1) * 64 + j, bf);
            pv = lo | (hi << 16);
        }
        pkN[l * LSN + idx] = pv;
    }
    for (int g = gid; g < 4 * 128; g += gthreads) {
        int l = g >> 7, r = g & 127;
        float v = (r < 64) ? gldf(nb1, l * 64 + r, bf) : gldf(nb2, l * 64 + (r - 64), bf);
        ((float*)(pkN + l * LSN + 6144))[r] = v;
    }
    __threadfence();
    grid.sync();

    // ---- P2: scan + perm counting-sort (block 0 only) ----
    if (bid == 0) {
        int* part  = (int*)sW;           // 512 ints
        int* hist  = part + 512;         // 32
        int* basep = hist + 32;          // 32
        const int CH = 40;               // 512*40 >= NN
        const int b0 = tid * CH;
        int s = 0;
        for (int i = 0; i < CH; i++) { int idx = b0 + i; if (idx < NN) s += cursor[idx]; }
        part[tid] = s;
        __syncthreads();
        for (int d = 1; d < 512; d <<= 1) {
            int v = (tid >= d) ? part[tid - d] : 0;
            __syncthreads();
            part[tid] += v;
            __syncthreads();
        }
        int run = (tid > 0) ? part[tid - 1] : 0;
        for (int i = 0; i < CH; i++) {
            int idx = b0 + i;
            if (idx < NN) {
                int dv = cursor[idx];
                offs[idx] = run;
                cursor[idx] = run;       // scatter cursor
                run += dv;
            }
        }
        if (tid == 511) offs[NN] = run;
        __syncthreads();
        if (tid < 32) hist[tid] = 0;
        __syncthreads();
        for (int i = 0; i < CH; i++) {
            int idx = b0 + i;
            if (idx < NN) {
                int dv = offs[idx + 1] - offs[idx];
                int key = min(31, (dv + 15) >> 4);
                atomicAdd(&hist[key], 1);
            }
        }
        __syncthreads();
        if (tid == 0) {
            int pos = 0;
            for (int k = 31; k >= 0; k--) { basep[k] = pos; pos += hist[k]; }
        }
        __syncthreads();
        for (int i = 0; i < CH; i++) {
            int idx = b0 + i;
            if (idx < NN) {
                int dv = offs[idx + 1] - offs[idx];
                int key = min(31, (dv + 15) >> 4);
                int p = atomicAdd(&basep[key], 1);
                perm[p] = idx;
            }
        }
    }
    __threadfence();
    grid.sync();

    // ---- P3: scatter + input embedding (independent) ----
    for (int e = gid; e < EE; e += gthreads) {
        int r = rowi[e];
        int pos = atomicAdd(&cursor[r], 1);
        slist[pos] = coli[e];
    }
    for (int n = waveid; n < NN; n += nwaves) {
        float acc = gldf(emb_b, lane, bf);
        #pragma unroll
        for (int k = 0; k < 16; k++)
            acc = fmaf(gldf(h_in, n * 16 + k, bf), gldf(emb_w, k * 64 + lane, bf), acc);
        hws[n * 64 + lane] = acc;
        hb[n * 64 + lane] = f2bf_rne(acc);
        if (lane < 3) xws[n * 3 + lane] = gldf(x_in, n * 3 + lane, bf);
    }
    __threadfence();
    grid.sync();

    // ---- layers ----
    u16* mrow = &sW[OFF_M + wv * 16 * MPAD];
    float* phiw = (float*)&sW[OFF_PHI + wv * 32];

    for (int l = 0; l < 4; l++) {
        // stage layer weights into LDS
        const u16* pEl = pkE + l * LSE;
        const u32* pNl = pkN + (size_t)l * LSN;
        for (int idx = tid; idx < 2048; idx += 512)
            ((s16x8*)sW)[idx] = ((const s16x8*)pEl)[idx];
        {
            const float* pb = (const float*)(pEl + 16384);
            float* cb = (float*)&sW[OFF_CB];
            if (tid < 320) cb[tid] = pb[tid];
        }
        for (int idx = tid; idx < 1568; idx += 512)
            ((f32x4*)&sW[OFF_NW])[idx] = ((const f32x4*)pNl)[idx];
        __syncthreads();

        const float* CB = (const float*)&sW[OFF_CB];
        const u32* nW1 = (const u32*)&sW[OFF_NW];
        const u32* nW2 = nW1 + 4096;
        const float* nB = (const float*)(nW1 + 6144);

        // ===== EDGE PHASE (R17 body verbatim; deg==0 writes zeros) =====
        const int gw = bid * 8 + wv, totW = gridDim.x * 8;
        for (int pidx = gw; pidx < NN; pidx += totW) {
            const int n = perm[pidx];
            const int o0 = offs[n], deg = offs[n + 1] - o0;
            if (deg == 0) {
                agg[n * 64 + lane] = 0.0f;
                if (l15 == 0 && quad < 3) xacc[n * 3 + quad] = 0.0f;
                continue;
            }
            const s16x8 Ar0 = *(const s16x8*)&hb[n * 64 + quad * 8];
            const s16x8 Ar1 = *(const s16x8*)&hb[n * 64 + 32 + quad * 8];
            f32x4 Cb[4] = {{0,0,0,0},{0,0,0,0},{0,0,0,0},{0,0,0,0}};
            #pragma unroll
            for (int t = 0; t < 4; t++) {
                const s16x8 Bf0 = *(const s16x8*)&sW[((0 * 4 + t) * 64 + lane) * 8];
                Cb[t] = __builtin_amdgcn_mfma_f32_16x16x32_bf16(Ar0, Bf0, Cb[t], 0, 0, 0);
                const s16x8 Bf1 = *(const s16x8*)&sW[((1 * 4 + t) * 64 + lane) * 8];
                Cb[t] = __builtin_amdgcn_mfma_f32_16x16x32_bf16(Ar1, Bf1, Cb[t], 0, 0, 0);
            }
            const float xrv = (quad < 3) ? xws[n * 3 + quad] : 0.0f;
            float aggA[4] = {0.f, 0.f, 0.f, 0.f};
            float xaccA = 0.0f;

            for (int eb = 0; eb < deg; eb += 16) {
                const int nb = min(16, deg - eb);
                const int ee = (l15 < nb) ? l15 : 0;
                const int ce = slist[o0 + eb + ee];
                float dx = 0.0f;
                if (quad < 3 && l15 < nb) dx = xrv - xws[ce * 3 + quad];
                float r2 = dx * dx;
                r2 += __shfl_xor(r2, 16, 64);
                r2 += __shfl_xor(r2, 32, 64);

                f32x4 C[4] = {Cb[0], Cb[1], Cb[2], Cb[3]};
                {
                    const s16x8 Ac0 = *(const s16x8*)&hb[ce * 64 + quad * 8];
                    const s16x8 Ac1 = *(const s16x8*)&hb[ce * 64 + 32 + quad * 8];
                    #pragma unroll
                    for (int t = 0; t < 4; t++) {
                        const s16x8 Bf2 = *(const s16x8*)&sW[((2 * 4 + t) * 64 + lane) * 8];
                        C[t] = __builtin_amdgcn_mfma_f32_16x16x32_bf16(Ac0, Bf2, C[t], 0, 0, 0);
                        const s16x8 Bf3 = *(const s16x8*)&sW[((3 * 4 + t) * 64 + lane) * 8];
                        C[t] = __builtin_amdgcn_mfma_f32_16x16x32_bf16(Ac1, Bf3, C[t], 0, 0, 0);
                    }
                }
                float r2r[4];
                #pragma unroll
                for (int r = 0; r < 4; r++) r2r[r] = __shfl(r2, quad * 4 + r, 64);
                #pragma unroll
                for (int t = 0; t < 4; t++) {
                    const float b1t = CB[       16 * t + l15];
                    const float wrt = CB[256 +  16 * t + l15];
                    #pragma unroll
                    for (int r = 0; r < 4; r++) {
                        float v = silu_f(C[t][r] + b1t + r2r[r] * wrt);
                        mrow[(quad * 4 + r) * MPAD + 16 * t + l15] = f2bf_rne(v);
                    }
                }

                f32x4 D[4] = {{0,0,0,0},{0,0,0,0},{0,0,0,0},{0,0,0,0}};
                #pragma unroll
                for (int w = 0; w < 2; w++) {
                    const s16x8 Am = *(const s16x8*)(mrow + l15 * MPAD + 32 * w + quad * 8);
                    #pragma unroll
                    for (int t = 0; t < 4; t++) {
                        const s16x8 Bf = *(const s16x8*)&sW[OFF_B23 + ((w * 4 + t) * 64 + lane) * 8];
                        D[t] = __builtin_amdgcn_mfma_f32_16x16x32_bf16(Am, Bf, D[t], 0, 0, 0);
                    }
                }
                #pragma unroll
                for (int t = 0; t < 4; t++) {
                    const float b2t = CB[64 + 16 * t + l15];
                    #pragma unroll
                    for (int r = 0; r < 4; r++) {
                        float v = silu_f(D[t][r] + b2t);
                        if (quad * 4 + r < nb) aggA[t] += v;
                        mrow[(quad * 4 + r) * MPAD + 16 * t + l15] = f2bf_rne(v);
                    }
                }

                f32x4 P[4] = {{0,0,0,0},{0,0,0,0},{0,0,0,0},{0,0,0,0}};
                #pragma unroll
                for (int w = 0; w < 2; w++) {
                    const s16x8 Am = *(const s16x8*)(mrow + l15 * MPAD + 32 * w + quad * 8);
                    #pragma unroll
                    for (int t = 0; t < 4; t++) {
                        const s16x8 Bf = *(const s16x8*)&sW[OFF_B23 + (((2 + w) * 4 + t) * 64 + lane) * 8];
                        P[t] = __builtin_amdgcn_mfma_f32_16x16x32_bf16(Am, Bf, P[t], 0, 0, 0);
                    }
                }
                float ph[4];
                #pragma unroll
                for (int r = 0; r < 4; r++) ph[r] = 0.f;
                #pragma unroll
                for (int t = 0; t < 4; t++) {
                    const float cb1t = CB[128 + 16 * t + l15];
                    const float c2t  = CB[192 + 16 * t + l15];
                    #pragma unroll
                    for (int r = 0; r < 4; r++)
                        ph[r] = fmaf(silu_f(P[t][r] + cb1t), c2t, ph[r]);
                }
                #pragma unroll
                for (int r = 0; r < 4; r++) {
                    float s = ph[r];
                    s += __shfl_xor(s, 1, 64);
                    s += __shfl_xor(s, 2, 64);
                    s += __shfl_xor(s, 4, 64);
                    s += __shfl_xor(s, 8, 64);
                    ph[r] = s;
                }
                if (l15 == 0) {
                    #pragma unroll
                    for (int r = 0; r < 4; r++) phiw[quad * 4 + r] = ph[r];
                }
                float phv = phiw[l15];
                if (quad < 3 && l15 < nb) xaccA = fmaf(dx, phv, xaccA);
            }

            #pragma unroll
            for (int t = 0; t < 4; t++) {
                aggA[t] += __shfl_xor(aggA[t], 16, 64);
                aggA[t] += __shfl_xor(aggA[t], 32, 64);
            }
            float av = (quad == 0) ? aggA[0] : (quad == 1) ? aggA[1]
                     : (quad == 2) ? aggA[2] : aggA[3];
            agg[n * 64 + lane] = av;

            xaccA += __shfl_xor(xaccA, 1, 64);
            xaccA += __shfl_xor(xaccA, 2, 64);
            xaccA += __shfl_xor(xaccA, 4, 64);
            xaccA += __shfl_xor(xaccA, 8, 64);
            if (l15 == 0 && quad < 3) xacc[n * 3 + quad] = xaccA / (float)deg;
        }
        __threadfence();
        grid.sync();

        // ===== NODE PHASE (k_node math, 4-node ILP chunks per wave) =====
        for (int i = gid; i < NN * 3; i += gthreads) xws[i] += xacc[i];

        float* nin = (float*)mrow;          // 4 nodes x 132 f32 = 2112B <= 2432B
        for (int base = waveid * 4; base < NN; base += nwaves * 4) {
            const int cnt = min(4, NN - base);
            float hvv[4] = {0.f, 0.f, 0.f, 0.f};
            #pragma unroll
            for (int c = 0; c < 4; c++) {
                if (c < cnt) {
                    int n = base + c;
                    float hv = hws[n * 64 + lane];
                    hvv[c] = hv;
                    nin[c * 132 + lane] = hv;
                    nin[c * 132 + 64 + lane] = agg[n * 64 + lane];
                }
            }
            float a1[4];
            #pragma unroll
            for (int c = 0; c < 4; c++) a1[c] = nB[lane];
            #pragma unroll
            for (int kk = 0; kk < 32; kk++) {
                u32 w01 = nW1[(kk * 2) * 64 + lane];
                u32 w23 = nW1[(kk * 2 + 1) * 64 + lane];
                float w0 = __uint_as_float(w01 << 16), w1 = __uint_as_float(w01 & 0xffff0000u);
                float w2 = __uint_as_float(w23 << 16), w3 = __uint_as_float(w23 & 0xffff0000u);
                #pragma unroll
                for (int c = 0; c < 4; c++) {
                    const float4 e4 = *reinterpret_cast<const float4*>(&nin[c * 132 + kk * 4]);
                    a1[c] = fmaf(e4.x, w0, fmaf(e4.y, w1, fmaf(e4.z, w2, fmaf(e4.w, w3, a1[c]))));
                }
            }
            #pragma unroll
            for (int c = 0; c < 4; c++) a1[c] = silu_f(a1[c]);
            #pragma unroll
            for (int c = 0; c < 4; c++) nin[c * 132 + lane] = a1[c];
            float a2[4];
            #pragma unroll
            for (int c = 0; c < 4; c++) a2[c] = nB[64 + lane];
            #pragma unroll
            for (int kk = 0; kk < 16; kk++) {
                u32 w01 = nW2[(kk * 2) * 64 + lane];
                u32 w23 = nW2[(kk * 2 + 1) * 64 + lane];
                float w0 = __uint_as_float(w01 << 16), w1 = __uint_as_float(w01 & 0xffff0000u);
                float w2 = __uint_as_float(w23 << 16), w3 = __uint_as_float(w23 & 0xffff0000u);
                #pragma unroll
                for (int c = 0; c < 4; c++) {
                    const float4 e4 = *reinterpret_cast<const float4*>(&nin[c * 132 + kk * 4]);
                    a2[c] = fmaf(e4.x, w0, fmaf(e4.y, w1, fmaf(e4.z, w2, fmaf(e4.w, w3, a2[c]))));
                }
            }
            #pragma unroll
            for (int c = 0; c < 4; c++) {
                if (c < cnt) {
                    int n = base + c;
                    float hnew = hvv[c] + a2[c];
                    hws[n * 64 + lane] = hnew;
                    hb[n * 64 + lane] = f2bf_rne(hnew);
                }
            }
        }
        __threadfence();
        grid.sync();
    }

    // ---- OUT PHASE (k_out math; 8 nodes/wave, 64/block) ----
    {
        u32* sWp = (u32*)sW;                 // 2048 u32
        float* sBf = (float*)(sWp + 2048);   // 64 f32
        for (int idx = tid; idx < 2048; idx += 512) {
            int kp = idx >> 6, j = idx & 63;
            u32 lo = gldb(wo, (kp * 2) * 64 + j, bf);
            u32 hi = gldb(wo, (kp * 2 + 1) * 64 + j, bf);
            sWp[idx] = lo | (hi << 16);
        }
        if (tid < 64) sBf[tid] = gldf(bo, tid, bf);
        __syncthreads();

        u16*   oh16 = (u16*)outp;
        float* ohf  = (float*)outp;
        u16*   ox16 = oh16 + (size_t)NN * 64;
        float* oxf  = ohf  + (size_t)NN * 64;
        float* sH = (float*)mrow;            // 8 x 68 f32 = 2176B <= 2432B

        for (int i0 = (bid * 8 + wv) * 8; i0 < NN; i0 += gridDim.x * 64) {
            float acc[8];
            #pragma unroll
            for (int b = 0; b < 8; b++) {
                int i = i0 + b;
                sH[b * 68 + lane] = (i < NN) ? hws[i * 64 + lane] : 0.f;
                acc[b] = sBf[lane];
            }
            #pragma unroll
            for (int kk = 0; kk < 16; kk++) {
                u32 w01 = sWp[(kk * 2) * 64 + lane];
                u32 w23 = sWp[(kk * 2 + 1) * 64 + lane];
                float w0 = __uint_as_float(w01 << 16), w1 = __uint_as_float(w01 & 0xffff0000u);
                float w2 = __uint_as_float(w23 << 16), w3 = __uint_as_float(w23 & 0xffff0000u);
                #pragma unroll
                for (int b = 0; b < 8; b++) {
                    const float4 e4 = *reinterpret_cast<const float4*>(&sH[b * 68 + kk * 4]);
                    acc[b] = fmaf(e4.x, w0, fmaf(e4.y, w1, fmaf(e4.z, w2, fmaf(e4.w, w3, acc[b]))));
                }
            }
            #pragma unroll
            for (int b = 0; b < 8; b++) {
                int i = i0 + b;
                if (i < NN) {
                    if (bf) {
                        oh16[i * 64 + lane] = f2bf_rne(acc[b]);
                        if (lane < 3) ox16[i * 3 + lane] = f2bf_rne(xws[i * 3 + lane]);
                    } else {
                        ohf[i * 64 + lane] = acc[b];
                        if (lane < 3) oxf[i * 3 + lane] = xws[i * 3 + lane];
                    }
                }
            }
        }
    }
}

extern "C" void kernel_launch(void* const* d_in, const int* in_sizes, int n_in,
                              void* d_out, int out_size, void* d_ws, size_t ws_size,
                              hipStream_t stream)
{
    const size_t WS_REQ = (size_t)NN * 134 * sizeof(float) + 64;
    if (ws_size < WS_REQ) {
        float sval = 1000.0f + (float)(ws_size >> 20);
        k_sentinel<<<(out_size + 255) / 256, 256, 0, stream>>>(
            (u16*)d_out, out_size, sval);
        return;
    }

    const void* h_in = d_in[0];
    const void* x_in = d_in[1];
    const int*  eidx = (const int*)d_in[2];
    const int* rowi = eidx;
    const int* coli = eidx + EE;

    float* ws   = (float*)d_ws;
    float* hws  = ws;                           // N*64
    float* xws  = hws + NN * 64;                // N*3
    float* agg  = xws + NN * 3;                 // N*64
    float* xacc = agg + NN * 64;                // N*3  (=134 floats/node total)

    // d_out scratch until out phase overwrites it (fp32 out = 5.36 MB)
    u16* hb     = (u16*)d_out;                  // N*64 bf16
    int* offs   = (int*)(hb + (size_t)NN * 64); // N+4
    int* slist  = offs + (NN + 4);              // E
    u16* pkE    = (u16*)(slist + EE);           // 4*LSE u16 (16B-aligned)
    u32* pkN    = (u32*)(pkE + 4 * LSE);        // 4*LSN u32
    int* cursor = (int*)(pkN + 4 * LSN);        // N
    int* perm   = cursor + NN;                  // N

    // deadlock-proof cooperative grid: query once, cache
    static int gridBlocks = 0;
    if (gridBlocks == 0) {
        int maxB = 0;
        hipError_t err = hipOccupancyMaxActiveBlocksPerMultiprocessor(&maxB, k_mega, 512, 0);
        if (err != hipSuccess || maxB < 1) maxB = 1;
        gridBlocks = (maxB >= 2) ? 512 : 256;
    }

    void* outp = d_out;
    void* args[] = {
        (void*)&h_in, (void*)&x_in, (void*)&rowi, (void*)&coli,
        (void*)&d_in[5], (void*)&d_in[6], (void*)&d_in[7], (void*)&d_in[8],
        (void*)&d_in[9], (void*)&d_in[10], (void*)&d_in[11],
        (void*)&d_in[12], (void*)&d_in[13], (void*)&d_in[14], (void*)&d_in[15],
        (void*)&d_in[3], (void*)&d_in[4], (void*)&d_in[16], (void*)&d_in[17],
        (void*)&hws, (void*)&xws, (void*)&agg, (void*)&xacc,
        (void*)&hb, (void*)&offs, (void*)&slist, (void*)&pkE, (void*)&pkN,
        (void*)&cursor, (void*)&perm, (void*)&outp
    };
    hipLaunchCooperativeKernel((void*)k_mega, dim3(gridBlocks), dim3(512),
                               args, 0, stream);
}

// Round 12
// 566.609 us; speedup vs baseline: 3.1361x; 3.1361x over previous
//
#include <hip/hip_runtime.h>
#include <hip/hip_bf16.h>

// EGNN forward, MI355X. fp32 tensors (runtime-detected, bf16 path kept).
// R22 = R17 (best-known, 550us) + 3 dispatch removals, hot loops untouched.
//  - R21 mega-kernel post-mortem: union-of-phases register allocation hit
//    VGPR 128 + 915MB spill traffic -> 1777us. Single-kernel fusion is dead.
//  - R20's boundary insight retained: ~20-25us per removed dispatch.
//    (1) agg/xacc memset dropped -- k_edge zero-writes deg==0 nodes.
//    (2) k_scatter + k_embed merged (independent; blocks 0..1249 scatter,
//        1250..6249 embed).
//    (3) k_out fused into l=3 k_node: identical block->node mapping, so
//        __syncthreads suffices. Output overwrites d_out scratch, so the
//        fused kernel stages node weights from RAW d_in (never overwritten),
//        not pkN. k_pack packs only 3 node layers.
//  - k_edge/k_node math byte-identical to R17 (67.5us k_edge, VGPR 56).
// ws (floats): hws[N*64] | xws[N*3] | agg[N*64] | xacc[N*3] | flag
// d_out scratch until out phase:
//   hb[N*64 bf16] | offs[N+4] | slist[E] | pkE[4*17024 u16] | pkN[3*6272 u32] |
//   cursor[N] | perm[N]

#define NN 20000
#define EE 320000
#define LSE 17024      // per-layer u16 stride, edge pack
#define LSN 6272       // per-layer u32 stride, node pack (layers 0..2 only)

typedef unsigned short u16;
typedef unsigned int   u32;
typedef __attribute__((ext_vector_type(8))) short s16x8;   // 8 bf16 (A/B frag)
typedef __attribute__((ext_vector_type(4))) float f32x4;   // C/D frag

__device__ __forceinline__ float bf2f(u16 u) { return __uint_as_float(((u32)u) << 16); }
// fast silu: v_exp + v_rcp (~1 ulp) instead of the precise-div sequence.
__device__ __forceinline__ float silu_f(float x) {
    return x * __builtin_amdgcn_rcpf(1.0f + __expf(-x));
}

__device__ __forceinline__ u16 f2bf_rne(float f) {
    u32 u = __float_as_uint(f);
    return (u16)((u + 0x7FFFu + ((u >> 16) & 1u)) >> 16);
}
__device__ __forceinline__ float gldf(const void* p, int i, int bf) {
    return bf ? bf2f(((const u16*)p)[i]) : ((const float*)p)[i];
}
__device__ __forceinline__ u16 gldb(const void* p, int i, int bf) {
    return bf ? ((const u16*)p)[i] : f2bf_rne(((const float*)p)[i]);
}

__global__ void k_sentinel(u16* __restrict__ out, int n, float v) {
    int t = blockIdx.x * 256 + threadIdx.x;
    if (t < n) out[t] = f2bf_rne(v);
}

// ---- fused: weight prepack (blocks 0..63) + degree count (blocks 64..) ----
__global__ __launch_bounds__(256) void k_pack(
    const void* __restrict__ ew1, const void* __restrict__ eb1,
    const void* __restrict__ ew2, const void* __restrict__ eb2,
    const void* __restrict__ cw1, const void* __restrict__ cb1,
    const void* __restrict__ cw2,
    const void* __restrict__ nw1, const void* __restrict__ nb1,
    const void* __restrict__ nw2, const void* __restrict__ nb2,
    const u16* __restrict__ h_raw, const int* __restrict__ rowi,
    int* __restrict__ flag, int* __restrict__ deg,
    u16* __restrict__ pkE, u32* __restrict__ pkN)
{
    if (blockIdx.x >= 64) {                    // degree-count blocks
        int e = (blockIdx.x - 64) * 256 + threadIdx.x;
        if (e < EE) atomicAdd(&deg[rowi[e]], 1);
        return;
    }
    __shared__ int cnt_s;
    if (threadIdx.x == 0) cnt_s = 0;
    __syncthreads();
    if (threadIdx.x < 128) {
        float v = fabsf(bf2f(h_raw[threadIdx.x]));
        if (v >= 0.015625f && v <= 16.0f) atomicAdd(&cnt_s, 1);
    }
    __syncthreads();
    const int bf = (cnt_s >= 96) ? 1 : 0;
    if (blockIdx.x == 0 && threadIdx.x == 0) *flag = bf;

    const int gid = blockIdx.x * 256 + threadIdx.x;
    const int stride = 64 * 256;

    // edge weights: 4 layers x 16384 u16
    for (int g = gid; g < 4 * 16384; g += stride) {
        int l = g >> 14, idx = g & 16383;
        u16 v;
        if (idx < 8192) {
            int j = idx & 7, lane = (idx >> 3) & 63, t = (idx >> 9) & 3, w = idx >> 11;
            int k = 32 * w + (lane >> 4) * 8 + j, n = 16 * t + (lane & 15);
            v = gldb(ew1, l * 129 * 64 + k * 64 + n, bf);
        } else if (idx < 12288) {
            int i2 = idx - 8192;
            int j = i2 & 7, lane = (i2 >> 3) & 63, t = (i2 >> 9) & 3, w = i2 >> 11;
            int k = 32 * w + (lane >> 4) * 8 + j, n = 16 * t + (lane & 15);
            v = gldb(ew2, l * 4096 + k * 64 + n, bf);
        } else {
            int i2 = idx - 12288;
            int j = i2 & 7, lane = (i2 >> 3) & 63, t = (i2 >> 9) & 3, w = i2 >> 11;
            int k = 32 * w + (lane >> 4) * 8 + j, n = 16 * t + (lane & 15);
            v = gldb(cw1, l * 4096 + k * 64 + n, bf);
        }
        pkE[l * LSE + idx] = v;
    }
    // edge fp32 consts: 4 layers x 320
    for (int g = gid; g < 4 * 320; g += stride) {
        int l = g / 320, r = g % 320, wch = r >> 6, i = r & 63;
        float v = (wch == 0) ? gldf(eb1, l * 64 + i, bf)
                : (wch == 1) ? gldf(eb2, l * 64 + i, bf)
                : (wch == 2) ? gldf(cb1, l * 64 + i, bf)
                : (wch == 3) ? gldf(cw2, l * 64 + i, bf)
                :              gldf(ew1, l * 129 * 64 + 128 * 64 + i, bf);
        ((float*)(pkE + l * LSE + 16384))[r] = v;
    }
    // node weights: layers 0..2 only (l=3 staged raw by k_node_out)
    for (int g = gid; g < 3 * 6144; g += stride) {
        int l = g / 6144, idx = g % 6144;
        u32 pv;
        if (idx < 4096) {
            int kp = idx >> 6, j = idx & 63;
            u32 lo = gldb(nw1, l * 8192 + (2 * kp) * 64 + j, bf);
            u32 hi = gldb(nw1, l * 8192 + (2 * kp + 1) * 64 + j, bf);
            pv = lo | (hi << 16);
        } else {
            int i2 = idx - 4096, kp = i2 >> 6, j = i2 & 63;
            u32 lo = gldb(nw2, l * 4096 + (2 * kp) * 64 + j, bf);
            u32 hi = gldb(nw2, l * 4096 + (2 * kp + 1) * 64 + j, bf);
            pv = lo | (hi << 16);
        }
        pkN[l * LSN + idx] = pv;
    }
    for (int g = gid; g < 3 * 128; g += stride) {
        int l = g >> 7, r = g & 127;
        float v = (r < 64) ? gldf(nb1, l * 64 + r, bf) : gldf(nb2, l * 64 + (r - 64), bf);
        ((float*)(pkN + l * LSN + 6144))[r] = v;
    }
}

// ---- CSR scan + balance schedule ----
__global__ __launch_bounds__(1024) void k_scan(const int* deg, int* offs, int* cursor,
                                               int* __restrict__ perm) {
    __shared__ int part[1024];
    __shared__ int hist[32], basep[32];
    const int tid = threadIdx.x;
    const int CH = (NN + 1023) / 1024;         // 20
    const int b0 = tid * CH;
    int s = 0;
    for (int i = 0; i < CH; i++) { int idx = b0 + i; if (idx < NN) s += deg[idx]; }
    part[tid] = s;
    __syncthreads();
    for (int d = 1; d < 1024; d <<= 1) {
        int v = (tid >= d) ? part[tid - d] : 0;
        __syncthreads();
        part[tid] += v;
        __syncthreads();
    }
    int run = (tid > 0) ? part[tid - 1] : 0;
    for (int i = 0; i < CH; i++) {
        int idx = b0 + i;
        if (idx < NN) {
            int dv = deg[idx];                  // read BEFORE overwrite (aliased)
            offs[idx] = run;
            cursor[idx] = run;
            run += dv;
        }
    }
    if (tid == 1023) offs[NN] = run;
    __syncthreads();

    if (tid < 32) hist[tid] = 0;
    __syncthreads();
    for (int i = 0; i < CH; i++) {
        int idx = b0 + i;
        if (idx < NN) {
            int dv = offs[idx + 1] - offs[idx];
            int key = min(31, (dv + 15) >> 4);
            atomicAdd(&hist[key], 1);
        }
    }
    __syncthreads();
    if (tid == 0) {
        int pos = 0;
        for (int k = 31; k >= 0; k--) { basep[k] = pos; pos += hist[k]; }
    }
    __syncthreads();
    for (int i = 0; i < CH; i++) {
        int idx = b0 + i;
        if (idx < NN) {
            int dv = offs[idx + 1] - offs[idx];
            int key = min(31, (dv + 15) >> 4);
            int p = atomicAdd(&basep[key], 1);
            perm[p] = idx;
        }
    }
}

// ---- merged scatter (blocks 0..1249) + input embedding (blocks 1250..) ----
__global__ __launch_bounds__(256) void k_scatem(
    const int* __restrict__ rowi, const int* __restrict__ coli,
    int* __restrict__ cursor, int* __restrict__ slist,
    const void* __restrict__ h_in, const void* __restrict__ x_in,
    const void* __restrict__ w, const void* __restrict__ bias,
    const int* __restrict__ flag,
    float* __restrict__ hws, float* __restrict__ xws, u16* __restrict__ hb)
{
    if (blockIdx.x < (EE + 255) / 256) {
        int e = blockIdx.x * 256 + threadIdx.x;
        if (e < EE) {
            int r = rowi[e];
            int pos = atomicAdd(&cursor[r], 1);
            slist[pos] = coli[e];
        }
        return;
    }
    const int bf = *flag;
    const int lane = threadIdx.x & 63;
    const int wv   = threadIdx.x >> 6;
    const int i    = (blockIdx.x - (EE + 255) / 256) * 4 + wv;
    float acc = gldf(bias, lane, bf);
    #pragma unroll
    for (int k = 0; k < 16; k++)
        acc = fmaf(gldf(h_in, i * 16 + k, bf), gldf(w, k * 64 + lane, bf), acc);
    hws[i * 64 + lane] = acc;
    hb[i * 64 + lane] = f2bf_rne(acc);
    if (lane < 3) xws[i * 3 + lane] = gldf(x_in, i * 3 + lane, bf);
}

// ---- edge model: R17 body verbatim + deg==0 zero-writes (replaces memset) ----
#define OFF_B23  8192
#define OFF_M    16384
#define MPAD     76
#define OFF_PHI  (OFF_M + 8 * 16 * MPAD)
#define OFF_CB   (OFF_PHI + 8 * 32)
__global__ __launch_bounds__(512, 8) void k_edge(
    const u16* __restrict__ hb, const float* __restrict__ xws,
    const int* __restrict__ offs, const int* __restrict__ slist,
    const u16* __restrict__ pE, const int* __restrict__ perm,
    float* __restrict__ agg, float* __restrict__ xacc)
{
    __shared__ __align__(16) u16 sW[OFF_CB + 640];

    const int tid = threadIdx.x, lane = tid & 63, wv = tid >> 6;
    const int l15 = lane & 15, quad = lane >> 4;

    for (int idx = tid; idx < 2048; idx += 512)
        ((s16x8*)sW)[idx] = ((const s16x8*)pE)[idx];
    {
        const float* pb = (const float*)(pE + 16384);
        float* cb = (float*)&sW[OFF_CB];
        if (tid < 320) cb[tid] = pb[tid];
    }
    __syncthreads();

    const float* CB = (const float*)&sW[OFF_CB];
    const int gw = blockIdx.x * 8 + wv, totW = gridDim.x * 8;
    u16* mrow = &sW[OFF_M + wv * 16 * MPAD];
    float* phiw = (float*)&sW[OFF_PHI + wv * 32];

    for (int pidx = gw; pidx < NN; pidx += totW) {
        const int n = perm[pidx];
        const int o0 = offs[n], deg = offs[n + 1] - o0;
        if (deg == 0) {
            agg[n * 64 + lane] = 0.0f;
            if (l15 == 0 && quad < 3) xacc[n * 3 + quad] = 0.0f;
            continue;
        }

        const s16x8 Ar0 = *(const s16x8*)&hb[n * 64 + quad * 8];
        const s16x8 Ar1 = *(const s16x8*)&hb[n * 64 + 32 + quad * 8];
        f32x4 Cb[4] = {{0,0,0,0},{0,0,0,0},{0,0,0,0},{0,0,0,0}};
        #pragma unroll
        for (int t = 0; t < 4; t++) {
            const s16x8 Bf0 = *(const s16x8*)&sW[((0 * 4 + t) * 64 + lane) * 8];
            Cb[t] = __builtin_amdgcn_mfma_f32_16x16x32_bf16(Ar0, Bf0, Cb[t], 0, 0, 0);
            const s16x8 Bf1 = *(const s16x8*)&sW[((1 * 4 + t) * 64 + lane) * 8];
            Cb[t] = __builtin_amdgcn_mfma_f32_16x16x32_bf16(Ar1, Bf1, Cb[t], 0, 0, 0);
        }
        const float xrv = (quad < 3) ? xws[n * 3 + quad] : 0.0f;
        float aggA[4] = {0.f, 0.f, 0.f, 0.f};
        float xaccA = 0.0f;

        for (int eb = 0; eb < deg; eb += 16) {
            const int nb = min(16, deg - eb);
            const int ee = (l15 < nb) ? l15 : 0;
            const int ce = slist[o0 + eb + ee];
            float dx = 0.0f;
            if (quad < 3 && l15 < nb) dx = xrv - xws[ce * 3 + quad];
            float r2 = dx * dx;
            r2 += __shfl_xor(r2, 16, 64);
            r2 += __shfl_xor(r2, 32, 64);

            f32x4 C[4] = {Cb[0], Cb[1], Cb[2], Cb[3]};
            {
                const s16x8 Ac0 = *(const s16x8*)&hb[ce * 64 + quad * 8];
                const s16x8 Ac1 = *(const s16x8*)&hb[ce * 64 + 32 + quad * 8];
                #pragma unroll
                for (int t = 0; t < 4; t++) {
                    const s16x8 Bf2 = *(const s16x8*)&sW[((2 * 4 + t) * 64 + lane) * 8];
                    C[t] = __builtin_amdgcn_mfma_f32_16x16x32_bf16(Ac0, Bf2, C[t], 0, 0, 0);
                    const s16x8 Bf3 = *(const s16x8*)&sW[((3 * 4 + t) * 64 + lane) * 8];
                    C[t] = __builtin_amdgcn_mfma_f32_16x16x32_bf16(Ac1, Bf3, C[t], 0, 0, 0);
                }
            }
            float r2r[4];
            #pragma unroll
            for (int r = 0; r < 4; r++) r2r[r] = __shfl(r2, quad * 4 + r, 64);
            #pragma unroll
            for (int t = 0; t < 4; t++) {
                const float b1t = CB[       16 * t + l15];
                const float wrt = CB[256 +  16 * t + l15];
                #pragma unroll
                for (int r = 0; r < 4; r++) {
                    float v = silu_f(C[t][r] + b1t + r2r[r] * wrt);
                    mrow[(quad * 4 + r) * MPAD + 16 * t + l15] = f2bf_rne(v);
                }
            }

            f32x4 D[4] = {{0,0,0,0},{0,0,0,0},{0,0,0,0},{0,0,0,0}};
            #pragma unroll
            for (int w = 0; w < 2; w++) {
                const s16x8 Am = *(const s16x8*)(mrow + l15 * MPAD + 32 * w + quad * 8);
                #pragma unroll
                for (int t = 0; t < 4; t++) {
                    const s16x8 Bf = *(const s16x8*)&sW[OFF_B23 + ((w * 4 + t) * 64 + lane) * 8];
                    D[t] = __builtin_amdgcn_mfma_f32_16x16x32_bf16(Am, Bf, D[t], 0, 0, 0);
                }
            }
            #pragma unroll
            for (int t = 0; t < 4; t++) {
                const float b2t = CB[64 + 16 * t + l15];
                #pragma unroll
                for (int r = 0; r < 4; r++) {
                    float v = silu_f(D[t][r] + b2t);
                    if (quad * 4 + r < nb) aggA[t] += v;
                    mrow[(quad * 4 + r) * MPAD + 16 * t + l15] = f2bf_rne(v);
                }
            }

            f32x4 P[4] = {{0,0,0,0},{0,0,0,0},{0,0,0,0},{0,0,0,0}};
            #pragma unroll
            for (int w = 0; w < 2; w++) {
                const s16x8 Am = *(const s16x8*)(mrow + l15 * MPAD + 32 * w + quad * 8);
                #pragma unroll
                for (int t = 0; t < 4; t++) {
                    const s16x8 Bf = *(const s16x8*)&sW[OFF_B23 + (((2 + w) * 4 + t) * 64 + lane) * 8];
                    P[t] = __builtin_amdgcn_mfma_f32_16x16x32_bf16(Am, Bf, P[t], 0, 0, 0);
                }
            }
            float ph[4];
            #pragma unroll
            for (int r = 0; r < 4; r++) ph[r] = 0.f;
            #pragma unroll
            for (int t = 0; t < 4; t++) {
                const float cb1t = CB[128 + 16 * t + l15];
                const float c2t  = CB[192 + 16 * t + l15];
                #pragma unroll
                for (int r = 0; r < 4; r++)
                    ph[r] = fmaf(silu_f(P[t][r] + cb1t), c2t, ph[r]);
            }
            #pragma unroll
            for (int r = 0; r < 4; r++) {
                float s = ph[r];
                s += __shfl_xor(s, 1, 64);
                s += __shfl_xor(s, 2, 64);
                s += __shfl_xor(s, 4, 64);
                s += __shfl_xor(s, 8, 64);
                ph[r] = s;
            }
            if (l15 == 0) {
                #pragma unroll
                for (int r = 0; r < 4; r++) phiw[quad * 4 + r] = ph[r];
            }
            float phv = phiw[l15];
            if (quad < 3 && l15 < nb) xaccA = fmaf(dx, phv, xaccA);
        }

        #pragma unroll
        for (int t = 0; t < 4; t++) {
            aggA[t] += __shfl_xor(aggA[t], 16, 64);
            aggA[t] += __shfl_xor(aggA[t], 32, 64);
        }
        float av = (quad == 0) ? aggA[0] : (quad == 1) ? aggA[1]
                 : (quad == 2) ? aggA[2] : aggA[3];
        agg[n * 64 + quad * 16 + l15] = av;

        xaccA += __shfl_xor(xaccA, 1, 64);
        xaccA += __shfl_xor(xaccA, 2, 64);
        xaccA += __shfl_xor(xaccA, 4, 64);
        xaccA += __shfl_xor(xaccA, 8, 64);
        if (l15 == 0 && quad < 3) xacc[n * 3 + quad] = xaccA / (float)deg;
    }
}

// ---- node model, layers 0..2 (R17 verbatim) ----
__global__ __launch_bounds__(256) void k_node(
    float* __restrict__ hws, u16* __restrict__ hb, const float* __restrict__ agg,
    float* __restrict__ xws, const float* __restrict__ xacc,
    const u32* __restrict__ pN)
{
    __shared__ __align__(16) u32 sW1p[64 * 64];
    __shared__ __align__(16) u32 sW2p[32 * 64];
    __shared__ float sB1f[64], sB2f[64];
    __shared__ __align__(16) float sNin[4][8][132];

    const int tid = threadIdx.x, lane = tid & 63, wv = tid >> 6;
    for (int idx = tid; idx < 1024; idx += 256)
        ((f32x4*)sW1p)[idx] = ((const f32x4*)pN)[idx];
    for (int idx = tid; idx < 512; idx += 256)
        ((f32x4*)sW2p)[idx] = ((const f32x4*)(pN + 4096))[idx];
    const float* pb = (const float*)(pN + 6144);
    if (tid < 64) { sB1f[tid] = pb[tid]; sB2f[tid] = pb[64 + tid]; }

    {
        int t = blockIdx.x * 96 + tid;
        if (tid < 96) xws[t] += xacc[t];
    }
    __syncthreads();

    const int i0 = (blockIdx.x * 4 + wv) * 8;
    float hold[8];
    #pragma unroll
    for (int b = 0; b < 8; b++) {
        int i = i0 + b;
        float hv = hws[i * 64 + lane];
        hold[b] = hv;
        sNin[wv][b][lane]      = hv;
        sNin[wv][b][64 + lane] = agg[i * 64 + lane];
    }

    float acc[8];
    #pragma unroll
    for (int b = 0; b < 8; b++) acc[b] = sB1f[lane];
    #pragma unroll
    for (int kk = 0; kk < 32; kk++) {
        u32 w01 = sW1p[(kk * 2) * 64 + lane];
        u32 w23 = sW1p[(kk * 2 + 1) * 64 + lane];
        float w0 = __uint_as_float(w01 << 16), w1 = __uint_as_float(w01 & 0xffff0000u);
        float w2 = __uint_as_float(w23 << 16), w3 = __uint_as_float(w23 & 0xffff0000u);
        #pragma unroll
        for (int b = 0; b < 8; b++) {
            const float4 e4 = *reinterpret_cast<const float4*>(&sNin[wv][b][kk * 4]);
            acc[b] = fmaf(e4.x, w0, fmaf(e4.y, w1, fmaf(e4.z, w2, fmaf(e4.w, w3, acc[b]))));
        }
    }
    #pragma unroll
    for (int b = 0; b < 8; b++) acc[b] = silu_f(acc[b]);
    #pragma unroll
    for (int b = 0; b < 8; b++) sNin[wv][b][lane] = acc[b];

    float out[8];
    #pragma unroll
    for (int b = 0; b < 8; b++) out[b] = sB2f[lane];
    #pragma unroll
    for (int kk = 0; kk < 16; kk++) {
        u32 w01 = sW2p[(kk * 2) * 64 + lane];
        u32 w23 = sW2p[(kk * 2 + 1) * 64 + lane];
        float w0 = __uint_as_float(w01 << 16), w1 = __uint_as_float(w01 & 0xffff0000u);
        float w2 = __uint_as_float(w23 << 16), w3 = __uint_as_float(w23 & 0xffff0000u);
        #pragma unroll
        for (int b = 0; b < 8; b++) {
            const float4 e4 = *reinterpret_cast<const float4*>(&sNin[wv][b][kk * 4]);
            out[b] = fmaf(e4.x, w0, fmaf(e4.y, w1, fmaf(e4.z, w2, fmaf(e4.w, w3, out[b]))));
        }
    }
    #pragma unroll
    for (int b = 0; b < 8; b++) {
        float hv = hold[b] + out[b];
        hws[(i0 + b) * 64 + lane] = hv;
        hb[(i0 + b) * 64 + lane] = f2bf_rne(hv);
    }
}

// ---- layer-3 node + output embedding, fused (weights staged from RAW d_in;
//      output may overwrite d_out scratch because nothing reads it again) ----
__global__ __launch_bounds__(256) void k_node_out(
    float* __restrict__ hws, const float* __restrict__ agg,
    float* __restrict__ xws, const float* __restrict__ xacc,
    const void* __restrict__ nw1, const void* __restrict__ nb1,
    const void* __restrict__ nw2, const void* __restrict__ nb2,
    const void* __restrict__ wo, const void* __restrict__ bo,
    const int* __restrict__ flag, void* __restrict__ outp)
{
    __shared__ __align__(16) u32 sW1p[64 * 64];
    __shared__ __align__(16) u32 sW2p[32 * 64];
    __shared__ float sB1f[64], sB2f[64];
    __shared__ __align__(16) float sNin[4][8][132];
    __shared__ __align__(16) u32 sWp[32 * 64];
    __shared__ float sBf[64];

    const int tid = threadIdx.x, lane = tid & 63, wv = tid >> 6;
    const int bf = *flag;

    // stage l=3 node weights from raw tensors (bf-aware bf16 k-pair pack)
    for (int idx = tid; idx < 4096; idx += 256) {
        int kp = idx >> 6, j = idx & 63;
        u32 lo = gldb(nw1, 3 * 8192 + (2 * kp) * 64 + j, bf);
        u32 hi = gldb(nw1, 3 * 8192 + (2 * kp + 1) * 64 + j, bf);
        sW1p[idx] = lo | (hi << 16);
    }
    for (int idx = tid; idx < 2048; idx += 256) {
        int kp = idx >> 6, j = idx & 63;
        u32 lo = gldb(nw2, 3 * 4096 + (2 * kp) * 64 + j, bf);
        u32 hi = gldb(nw2, 3 * 4096 + (2 * kp + 1) * 64 + j, bf);
        sW2p[idx] = lo | (hi << 16);
    }
    if (tid < 64) {
        sB1f[tid] = gldf(nb1, 3 * 64 + tid, bf);
        sB2f[tid] = gldf(nb2, 3 * 64 + tid, bf);
        sBf[tid]  = gldf(bo, tid, bf);
    }
    for (int idx = tid; idx < 2048; idx += 256) {
        int kp = idx >> 6, j = idx & 63;
        u32 lo = gldb(wo, (kp * 2) * 64 + j, bf);
        u32 hi = gldb(wo, (kp * 2 + 1) * 64 + j, bf);
        sWp[idx] = lo | (hi << 16);
    }

    {
        int t = blockIdx.x * 96 + tid;
        if (tid < 96) xws[t] += xacc[t];
    }
    __syncthreads();

    const int i0 = (blockIdx.x * 4 + wv) * 8;
    float hold[8];
    #pragma unroll
    for (int b = 0; b < 8; b++) {
        int i = i0 + b;
        float hv = hws[i * 64 + lane];
        hold[b] = hv;
        sNin[wv][b][lane]      = hv;
        sNin[wv][b][64 + lane] = agg[i * 64 + lane];
    }

    float acc[8];
    #pragma unroll
    for (int b = 0; b < 8; b++) acc[b] = sB1f[lane];
    #pragma unroll
    for (int kk = 0; kk < 32; kk++) {
        u32 w01 = sW1p[(kk * 2) * 64 + lane];
        u32 w23 = sW1p[(kk * 2 + 1) * 64 + lane];
        float w0 = __uint_as_float(w01 << 16), w1 = __uint_as_float(w01 & 0xffff0000u);
        float w2 = __uint_as_float(w23 << 16), w3 = __uint_as_float(w23 & 0xffff0000u);
        #pragma unroll
        for (int b = 0; b < 8; b++) {
            const float4 e4 = *reinterpret_cast<const float4*>(&sNin[wv][b][kk * 4]);
            acc[b] = fmaf(e4.x, w0, fmaf(e4.y, w1, fmaf(e4.z, w2, fmaf(e4.w, w3, acc[b]))));
        }
    }
    #pragma unroll
    for (int b = 0; b < 8; b++) acc[b] = silu_f(acc[b]);
    #pragma unroll
    for (int b = 0; b < 8; b++) sNin[wv][b][lane] = acc[b];

    float out[8];
    #pragma unroll
    for (int b = 0; b < 8; b++) out[b] = sB2f[lane];
    #pragma unroll
    for (int kk = 0; kk < 16; kk++) {
        u32 w01 = sW2p[(kk * 2) * 64 + lane];
        u32 w23 = sW2p[(kk * 2 + 1) * 64 + lane];
        float w0 = __uint_as_float(w01 << 16), w1 = __uint_as_float(w01 & 0xffff0000u);
        float w2 = __uint_as_float(w23 << 16), w3 = __uint_as_float(w23 & 0xffff0000u);
        #pragma unroll
        for (int b = 0; b < 8; b++) {
            const float4 e4 = *reinterpret_cast<const float4*>(&sNin[wv][b][kk * 4]);
            out[b] = fmaf(e4.x, w0, fmaf(e4.y, w1, fmaf(e4.z, w2, fmaf(e4.w, w3, out[b]))));
        }
    }
    // final h (no hb shadow needed); reuse sNin as the out-phase input tile
    #pragma unroll
    for (int b = 0; b < 8; b++) {
        float hv = hold[b] + out[b];
        hws[(i0 + b) * 64 + lane] = hv;
        sNin[wv][b][lane] = hv;
    }

    // ---- fused output embedding (same 32 nodes as this block's MLP) ----
    float acc2[8];
    #pragma unroll
    for (int b = 0; b < 8; b++) acc2[b] = sBf[lane];
    #pragma unroll
    for (int kk = 0; kk < 16; kk++) {
        u32 w01 = sWp[(kk * 2) * 64 + lane];
        u32 w23 = sWp[(kk * 2 + 1) * 64 + lane];
        float w0 = __uint_as_float(w01 << 16), w1 = __uint_as_float(w01 & 0xffff0000u);
        float w2 = __uint_as_float(w23 << 16), w3 = __uint_as_float(w23 & 0xffff0000u);
        #pragma unroll
        for (int b = 0; b < 8; b++) {
            const float4 e4 = *reinterpret_cast<const float4*>(&sNin[wv][b][kk * 4]);
            acc2[b] = fmaf(e4.x, w0, fmaf(e4.y, w1, fmaf(e4.z, w2, fmaf(e4.w, w3, acc2[b]))));
        }
    }
    u16*   oh16 = (u16*)outp;
    float* ohf  = (float*)outp;
    u16*   ox16 = oh16 + (size_t)NN * 64;
    float* oxf  = ohf  + (size_t)NN * 64;
    #pragma unroll
    for (int b = 0; b < 8; b++) {
        int i = i0 + b;
        if (bf) {
            oh16[i * 64 + lane] = f2bf_rne(acc2[b]);
            if (lane < 3) ox16[i * 3 + lane] = f2bf_rne(xws[i * 3 + lane]);
        } else {
            ohf[i * 64 + lane] = acc2[b];
            if (lane < 3) oxf[i * 3 + lane] = xws[i * 3 + lane];
        }
    }
}

extern "C" void kernel_launch(void* const* d_in, const int* in_sizes, int n_in,
                              void* d_out, int out_size, void* d_ws, size_t ws_size,
                              hipStream_t stream)
{
    const size_t WS_REQ = (size_t)NN * 134 * sizeof(float) + 64;
    if (ws_size < WS_REQ) {
        float sval = 1000.0f + (float)(ws_size >> 20);
        k_sentinel<<<(out_size + 255) / 256, 256, 0, stream>>>(
            (u16*)d_out, out_size, sval);
        return;
    }

    const void* h_in = d_in[0];
    const void* x_in = d_in[1];
    const int*  eidx = (const int*)d_in[2];
    const int* rowi = eidx;
    const int* coli = eidx + EE;

    float* ws   = (float*)d_ws;
    float* hws  = ws;                          // N*64
    float* xws  = hws + NN * 64;               // N*3
    float* agg  = xws + NN * 3;                // N*64
    float* xacc = agg + NN * 64;               // N*3
    int*   flag = (int*)(xacc + NN * 3);       // 1

    // d_out scratch until k_node_out overwrites it (fp32 out = 5.36 MB)
    u16* hb     = (u16*)d_out;                 // N*64 bf16
    int* offs   = (int*)(hb + (size_t)NN * 64);// N+4
    int* slist  = offs + (NN + 4);             // E
    u16* pkE    = (u16*)(slist + EE);          // 4*LSE u16 (16B-aligned)
    u32* pkN    = (u32*)(pkE + 4 * LSE);       // 3*LSN u32
    int* cursor = (int*)(pkN + 3 * LSN);       // N
    int* perm   = cursor + NN;                 // N

    hipMemsetAsync(cursor, 0, (size_t)NN * sizeof(int), stream);

    k_pack<<<64 + (EE + 255) / 256, 256, 0, stream>>>(
        d_in[5], d_in[6], d_in[7], d_in[8], d_in[9], d_in[10], d_in[11],
        d_in[12], d_in[13], d_in[14], d_in[15],
        (const u16*)h_in, rowi, flag, cursor, pkE, pkN);
    k_scan<<<1, 1024, 0, stream>>>(cursor, offs, cursor, perm);
    k_scatem<<<(EE + 255) / 256 + NN / 4, 256, 0, stream>>>(
        rowi, coli, cursor, slist,
        h_in, x_in, d_in[3], d_in[4], flag, hws, xws, hb);

    for (int l = 0; l < 4; l++) {
        k_edge<<<768, 512, 0, stream>>>(hb, xws, offs, slist,
                                        pkE + l * LSE, perm, agg, xacc);
        if (l < 3)
            k_node<<<NN / 32, 256, 0, stream>>>(hws, hb, agg, xws, xacc,
                                                pkN + (size_t)l * LSN);
    }
    k_node_out<<<NN / 32, 256, 0, stream>>>(hws, agg, xws, xacc,
                                            d_in[12], d_in[13], d_in[14], d_in[15],
                                            d_in[16], d_in[17], flag, d_out);
}